// Round 11
// baseline (90.752 us; speedup 1.0000x reference)
//
#include <hip/hip_runtime.h>
#include <math.h>

#define WIN 11
#define HALF 5
#define SZ 32
#define PST 33          /* padded LDS row stride */
#define BB 4
#define NG 16
#define NP 64
#define IH 640
#define IW 640
#define CPIX 1024       /* 32*32 per channel */
#define NPIX 3072       /* 3*32*32 per crop */
#define NCROP 320       /* 64 gt + 256 pred */
#define NPAIR 4096      /* 4*16*64 */
#define NSLOT 512       /* k_pair y-blocks per channel */
#define HROWS 21        /* 16 output rows + 5-row halo */
#define SSIM_C1 6.5025f
#define SSIM_C2 58.5225f

// exp(-(i-5)^2/4.5)/sum — 11-tap Gaussian, sigma=1.5, compile-time
#define GW_INIT {0.001028379f, 0.007598757f, 0.036000791f, 0.109360748f, \
                 0.213005174f, 0.266011868f, 0.213005174f, 0.109360748f, \
                 0.036000791f, 0.007598757f, 0.001028379f}

// Session lessons encoded:
//  - NO __threadfence (r5: device-scope fence flushes per-XCD L2; +100 µs over 1.5k blocks).
//  - NO contended fp atomicAdd accumulation (r2/r6 vs r3/r7: +16 µs); unique-cell
//    stores + tiny reduce kernel.
//  - NO memset dispatch: ballot compaction writes count/list with plain stores.
//  - r8: do NOT re-gather crops per pair (scattered gathers are the expensive op).
//  - r9: do NOT move per-crop stats into the per-pair kernel (2.8x conv work).
//  - r10: float2 bilinear gather (16->8 loads) = small win; gathers mostly latency-hidden.
//  - r11: halo-split crop blocks x2 (21-row slab incl. 5-row halo): doubles wave
//    occupancy during the cold-gather phase (3.75 -> 7.5 waves/SIMD) for 1.31x
//    gather volume; gather+h-conv is wave-synchronous (row = 8 lanes of one wave).

__device__ __forceinline__ bool pair_valid(const float* __restrict__ gt,
                                           const float* __restrict__ pr, int idx) {
    int b = idx >> 10;
    int r = idx & 1023;
    int gi = r >> 6, pi = r & 63;
    const float* g = gt + (b * NG + gi) * 4;
    const float* p = pr + (b * NP + pi) * 4;
    float gx = g[0], gy = g[1], gw = g[2], gh = g[3];
    float px = p[0], py = p[1], pw = p[2], ph = p[3];
    float tlx = fmaxf(gx - gw * 0.5f, px - pw * 0.5f);
    float tly = fmaxf(gy - gh * 0.5f, py - ph * 0.5f);
    float brx = fminf(gx + gw * 0.5f, px + pw * 0.5f);
    float bry = fminf(gy + gh * 0.5f, py + ph * 0.5f);
    float en = ((tlx < brx) && (tly < bry)) ? 1.f : 0.f;
    float ai = (brx - tlx) * (bry - tly) * en;
    float iou = ai / (gw * gh + pw * ph - ai + 1e-16f);
    return (iou > 0.3f && pw > 2.f && ph > 2.f);
}

// ---- fused: half-crop + mu/sigma (blocks 0..1919) | validity compaction (block 1920) ----
__global__ __launch_bounds__(256) void k_crop_valid(const float* __restrict__ imgs,
                                                    const float* __restrict__ gt,
                                                    const float* __restrict__ pr,
                                                    float* __restrict__ crops,
                                                    float* __restrict__ mus,
                                                    float* __restrict__ sigs,
                                                    int* __restrict__ list,
                                                    int* __restrict__ count) {
    const int blk = blockIdx.x;
    const int t = threadIdx.x;
    const int wave = t >> 6, lane = t & 63;

    if (blk == 6 * NCROP) {
        // ---- validity -> compact list: 2-pass wave-local ballot, 1 barrier ----
        __shared__ int s_wcnt[4];
        int cnt = 0;
#pragma unroll 1
        for (int i = 0; i < 16; ++i) {
            unsigned long long m = __ballot(pair_valid(gt, pr, wave * 1024 + i * 64 + lane));
            cnt += __popcll(m);
        }
        if (lane == 0) s_wcnt[wave] = cnt;
        __syncthreads();
        int base = 0;
#pragma unroll
        for (int w = 0; w < 4; ++w)
            if (w < wave) base += s_wcnt[w];
#pragma unroll 1
        for (int i = 0; i < 16; ++i) {
            int idx = wave * 1024 + i * 64 + lane;
            bool v = pair_valid(gt, pr, idx);
            unsigned long long m = __ballot(v);
            if (v) list[base + __popcll(m & ((1ull << lane) - 1ull))] = idx;
            base += __popcll(m);
        }
        if (t == 0) *count = s_wcnt[0] + s_wcnt[1] + s_wcnt[2] + s_wcnt[3];
        return;
    }

    // ---- half-crop path: seg 0 -> output rows 0..15, seg 1 -> rows 16..31 ----
    const int cc = blk >> 1;           // crop-channel 0..959
    const int seg = blk & 1;
    const int crop = cc / 3;
    const int c = cc - crop * 3;
    int b;
    const float* box;
    if (crop < BB * NG) {
        b = crop >> 4;
        box = gt + crop * 4;
    } else {
        int id = crop - BB * NG;
        b = id >> 6;
        box = pr + id * 4;
    }

    __shared__ float cr[HROWS][PST];
    __shared__ float t1[HROWS][PST];
    __shared__ float t2[HROWS][PST];

    // box is wave-uniform -> scalar loads
    float cx = box[0], cy = box[1], bw = box[2], bh = box[3];
    float x0 = fminf(fmaxf(floorf(cx - bw * 0.5f), 0.f), (float)(IW - 1));
    float x1 = fminf(fmaxf(floorf(cx + bw * 0.5f), 0.f), (float)IW);
    float y0 = fminf(fmaxf(floorf(cy - bh * 0.5f), 0.f), (float)(IH - 1));
    float y1 = fminf(fmaxf(floorf(cy + bh * 0.5f), 0.f), (float)IH);
    float wp = fmaxf(x1 - x0, 1.f);
    float hp = fmaxf(y1 - y0, 1.f);
    int xmax = (int)(x0 + wp - 1.f);
    int ymax = (int)(y0 + hp - 1.f);

    const int hbase = seg ? 11 : 0;    // global crop row of slab row 0
    const int r = t >> 3;              // slab row 0..31 (active < HROWS)
    const int xb = (t & 7) * 4;
    const float* ic = imgs + ((size_t)b * 3 + c) * IH * IW;
    constexpr float GW[WIN] = GW_INIT;

    if (r < HROWS) {
        const int gy = hbase + r;      // global crop row
        float sy = y0 + fminf(fmaxf(((float)gy + 0.5f) * hp * (1.f / 32.f) - 0.5f, 0.f), hp - 1.f);
        float fly = floorf(sy);
        int iy0 = (int)fly;
        float fy = sy - fly;
        int iy1 = min(iy0 + 1, ymax);
        const float* r0 = ic + iy0 * IW;
        const float* r1 = ic + iy1 * IW;
        float vv[4];
#pragma unroll
        for (int j = 0; j < 4; ++j) {
            int x = xb + j;
            float sx = x0 + fminf(fmaxf(((float)x + 0.5f) * wp * (1.f / 32.f) - 0.5f, 0.f), wp - 1.f);
            float flx = floorf(sx);
            int ix0 = (int)flx;
            float fx = sx - flx;
            // float2 gather (r10): clamp edge has weight exactly 0 -> bitwise identical
            int ixb = max(min(ix0, xmax - 1), 0);
            bool cl = (ix0 > ixb);
            float2 q0 = *(const float2*)(r0 + ixb);
            float2 q1 = *(const float2*)(r1 + ixb);
            float v00 = cl ? q0.y : q0.x;
            float v01 = q0.y;
            float v10 = cl ? q1.y : q1.x;
            float v11 = q1.y;
            vv[j] = v00 * (1.f - fy) * (1.f - fx) + v01 * (1.f - fy) * fx +
                    v10 * fy * (1.f - fx) + v11 * fy * fx;
            cr[r][x] = vv[j];
        }
        // crop store only for this segment's output rows
        if (gy >= seg * 16 && gy < seg * 16 + 16) {
            float* dst = crops + (size_t)crop * NPIX + c * CPIX + gy * SZ + xb;
            *(float4*)dst = make_float4(vv[0], vv[1], vv[2], vv[3]);
        }
        // wave-synchronous h-conv: row r was written by 8 lanes of THIS wave
        // (8 | 64), ds ordering within a wave is program order (lgkmcnt).
#pragma unroll
        for (int j = 0; j < 4; ++j) {
            int x = xb + j;
            float a1 = 0.f, a2 = 0.f;
#pragma unroll
            for (int k = 0; k < WIN; ++k) {
                int xx = x + k - HALF;
                if (xx >= 0 && xx < SZ) {
                    float v = cr[r][xx];
                    a1 += GW[k] * v;
                    a2 += GW[k] * v * v;
                }
            }
            t1[r][x] = a1;
            t2[r][x] = a2;
        }
    }
    __syncthreads();   // v-conv reads t1/t2 rows written by other waves

    if (t < 128) {
        const int q = t >> 3;          // 0..15
        const int oy = seg * 16 + q;   // global output row
        const int xb2 = (t & 7) * 4;
        float m[4], s[4];
#pragma unroll
        for (int j = 0; j < 4; ++j) {
            int x = xb2 + j;
            float a1 = 0.f, a2 = 0.f;
#pragma unroll
            for (int k = 0; k < WIN; ++k) {
                int yy = oy + k - HALF;
                if (yy >= 0 && yy < SZ) {
                    int rr = yy - hbase;   // guaranteed in [0, HROWS)
                    a1 += GW[k] * t1[rr][x];
                    a2 += GW[k] * t2[rr][x];
                }
            }
            m[j] = a1;
            s[j] = a2 - a1 * a1;
        }
        float* mdst = mus + (size_t)crop * NPIX + c * CPIX + oy * SZ + xb2;
        float* sdst = sigs + (size_t)crop * NPIX + c * CPIX + oy * SZ + xb2;
        *(float4*)mdst = make_float4(m[0], m[1], m[2], m[3]);
        *(float4*)sdst = make_float4(s[0], s[1], s[2], s[3]);
    }
}

// ---- per-(valid-pair, channel) SSIM + L1; unique-cell stores (r3/r7-measured-fast) ----
__global__ __launch_bounds__(256) void k_pair(const int* __restrict__ list,
                                              const int* __restrict__ count,
                                              const float* __restrict__ crops,
                                              const float* __restrict__ mus,
                                              const float* __restrict__ sigs,
                                              float* __restrict__ pairL1,
                                              float* __restrict__ pairSS) {
    const int c = blockIdx.x;      // 0..2
    const int n = *count;
    const int t = threadIdx.x;
    const int y = t >> 3;
    const int xb = (t & 7) * 4;
    const int wave = t >> 6, lane = t & 63;

    __shared__ float gp[SZ][PST];
    __shared__ float tmp[SZ][PST];
    __shared__ float rl[4], rs[4];
    constexpr float GW[WIN] = GW_INIT;

    for (int slot = blockIdx.y; slot < n; slot += NSLOT) {
        const int pair = list[slot];
        const int b = pair >> 10;
        const int r = pair & 1023;
        const int gi = r >> 6, pi = r & 63;
        const size_t goff = (size_t)(b * NG + gi) * NPIX + c * CPIX;
        const size_t poff = (size_t)(BB * NG + b * NP + pi) * NPIX + c * CPIX;

        float4 gv = *(const float4*)(crops + goff + t * 4);
        float4 pv = *(const float4*)(crops + poff + t * 4);
        // hoist mu/sigma loads: in flight across both conv phases
        float4 mg = *(const float4*)(mus + goff + t * 4);
        float4 mp = *(const float4*)(mus + poff + t * 4);
        float4 sg = *(const float4*)(sigs + goff + t * 4);
        float4 sp = *(const float4*)(sigs + poff + t * 4);

        float l1 = fabsf(gv.x - pv.x) + fabsf(gv.y - pv.y) +
                   fabsf(gv.z - pv.z) + fabsf(gv.w - pv.w);
        gp[y][xb + 0] = gv.x * pv.x;
        gp[y][xb + 1] = gv.y * pv.y;
        gp[y][xb + 2] = gv.z * pv.z;
        gp[y][xb + 3] = gv.w * pv.w;
        __syncthreads();

#pragma unroll
        for (int j = 0; j < 4; ++j) {
            int x = xb + j;
            float a = 0.f;
#pragma unroll
            for (int k = 0; k < WIN; ++k) {
                int xx = x + k - HALF;
                if (xx >= 0 && xx < SZ) a += GW[k] * gp[y][xx];
            }
            tmp[y][x] = a;
        }
        __syncthreads();

        float mgv[4] = {mg.x, mg.y, mg.z, mg.w};
        float mpv[4] = {mp.x, mp.y, mp.z, mp.w};
        float sgv[4] = {sg.x, sg.y, sg.z, sg.w};
        float spv[4] = {sp.x, sp.y, sp.z, sp.w};
        float ss = 0.f;
#pragma unroll
        for (int j = 0; j < 4; ++j) {
            int x = xb + j;
            float a = 0.f;
#pragma unroll
            for (int k = 0; k < WIN; ++k) {
                int yy = y + k - HALF;
                if (yy >= 0 && yy < SZ) a += GW[k] * tmp[yy][x];
            }
            float m1 = mgv[j], m2 = mpv[j];
            float sgp = a - m1 * m2;
            float num = (2.f * m1 * m2 + SSIM_C1) * (2.f * sgp + SSIM_C2);
            float den = (m1 * m1 + m2 * m2 + SSIM_C1) * (sgv[j] + spv[j] + SSIM_C2);
            ss += num / den;
        }

        // block reduction: 64-lane shuffle, then LDS across 4 waves
#pragma unroll
        for (int off = 32; off > 0; off >>= 1) {
            l1 += __shfl_down(l1, off);
            ss += __shfl_down(ss, off);
        }
        if (lane == 0) { rl[wave] = l1; rs[wave] = ss; }
        __syncthreads();
        if (t == 0) {
            pairL1[slot * 3 + c] = rl[0] + rl[1] + rl[2] + rl[3];
            pairSS[slot * 3 + c] = rs[0] + rs[1] + rs[2] + rs[3];
        }
    }
}

// ---- finalize: deterministic reduction over compact results ----
__global__ __launch_bounds__(256) void k_final(const int* __restrict__ count,
                                               const float* __restrict__ pairL1,
                                               const float* __restrict__ pairSS,
                                               float* __restrict__ out) {
    const int n3 = (*count) * 3;
    const int t = threadIdx.x;
    float L = 0.f, S = 0.f;
    for (int i = t; i < n3; i += 256) {
        L += pairL1[i];
        S += pairSS[i];
    }
    __shared__ float rl[4], rs[4];
#pragma unroll
    for (int off = 32; off > 0; off >>= 1) {
        L += __shfl_down(L, off);
        S += __shfl_down(S, off);
    }
    const int wave = t >> 6, lane = t & 63;
    if (lane == 0) { rl[wave] = L; rs[wave] = S; }
    __syncthreads();
    if (t == 0) {
        float cnt = (float)(*count);
        float Lt = (rl[0] + rl[1] + rl[2] + rl[3]) * (1.0f / (255.0f * (float)NPIX));
        float St = (rs[0] + rs[1] + rs[2] + rs[3]) * (1.0f / (float)NPIX);
        float m = fmaxf(cnt, 1.f);
        float loss = Lt / m + 1.f - St / m;
        out[0] = (cnt > 0.f) ? loss : 0.f;
    }
}

extern "C" void kernel_launch(void* const* d_in, const int* in_sizes, int n_in,
                              void* d_out, int out_size, void* d_ws, size_t ws_size,
                              hipStream_t stream) {
    const float* imgs = (const float*)d_in[0];  // (4,3,640,640)
    const float* gt = (const float*)d_in[1];    // (4,16,4)
    const float* pr = (const float*)d_in[2];    // (4,64,4)

    float* ws = (float*)d_ws;
    float* crops = ws;                                   // 320*3072
    float* mus = crops + (size_t)NCROP * NPIX;
    float* sigs = mus + (size_t)NCROP * NPIX;
    float* pairL1 = sigs + (size_t)NCROP * NPIX;         // 4096*3
    float* pairSS = pairL1 + (size_t)NPAIR * 3;          // 4096*3
    int* list = (int*)(pairSS + (size_t)NPAIR * 3);      // 4096
    int* count = list + NPAIR;                           // 1

    k_crop_valid<<<6 * NCROP + 1, 256, 0, stream>>>(imgs, gt, pr, crops, mus, sigs,
                                                    list, count);
    k_pair<<<dim3(3, NSLOT), 256, 0, stream>>>(list, count, crops, mus, sigs,
                                               pairL1, pairSS);
    k_final<<<1, 256, 0, stream>>>(count, pairL1, pairSS, (float*)d_out);
}

// Round 12
// 88.730 us; speedup vs baseline: 1.0228x; 1.0228x over previous
//
#include <hip/hip_runtime.h>
#include <math.h>

#define WIN 11
#define HALF 5
#define SZ 32
#define PST 33          /* padded LDS row stride */
#define BB 4
#define NG 16
#define NP 64
#define IH 640
#define IW 640
#define CPIX 1024       /* 32*32 per channel */
#define NPIX 3072       /* 3*32*32 per crop */
#define NCROP 320       /* 64 gt + 256 pred */
#define NPAIR 4096      /* 4*16*64 */
#define NSLOT 512       /* k_pair y-blocks per channel */
#define SSIM_C1 6.5025f
#define SSIM_C2 58.5225f

// exp(-(i-5)^2/4.5)/sum — 11-tap Gaussian, sigma=1.5, compile-time
#define GW_INIT {0.001028379f, 0.007598757f, 0.036000791f, 0.109360748f, \
                 0.213005174f, 0.266011868f, 0.213005174f, 0.109360748f, \
                 0.036000791f, 0.007598757f, 0.001028379f}

// Session lessons encoded:
//  - NO __threadfence (r5: device-scope fence flushes per-XCD L2; +100 µs over 1.5k blocks).
//  - NO contended fp atomicAdd accumulation (r2/r6 vs r3/r7: +16 µs); unique-cell
//    stores + tiny reduce kernel.
//  - NO memset dispatch: ballot compaction writes count/list with plain stores.
//  - r8: do NOT re-gather crops per pair (scattered gathers are the expensive op).
//  - r9: do NOT move per-crop stats into the per-pair kernel (2.8x conv work).
//  - r10: float2 bilinear gather (16->8 loads) = small win (~1 µs).
//  - r11: halo-split x2 regressed (+3.3 µs): 1.31x gathers + half-idle threads beat
//    the occupancy gain. BUT it HW-validated wave-synchronous LDS rows (8 thr/row,
//    8|64 -> one wave; DS ops program-ordered per wave).
//  - r12: apply that: drop the wave-local barriers (k_crop gather->h-conv,
//    k_pair gp-fill->h-conv). Each wave flows from its own gathers into h-conv
//    without stalling for the block's slowest wave.

__device__ __forceinline__ bool pair_valid(const float* __restrict__ gt,
                                           const float* __restrict__ pr, int idx) {
    int b = idx >> 10;
    int r = idx & 1023;
    int gi = r >> 6, pi = r & 63;
    const float* g = gt + (b * NG + gi) * 4;
    const float* p = pr + (b * NP + pi) * 4;
    float gx = g[0], gy = g[1], gw = g[2], gh = g[3];
    float px = p[0], py = p[1], pw = p[2], ph = p[3];
    float tlx = fmaxf(gx - gw * 0.5f, px - pw * 0.5f);
    float tly = fmaxf(gy - gh * 0.5f, py - ph * 0.5f);
    float brx = fminf(gx + gw * 0.5f, px + pw * 0.5f);
    float bry = fminf(gy + gh * 0.5f, py + ph * 0.5f);
    float en = ((tlx < brx) && (tly < bry)) ? 1.f : 0.f;
    float ai = (brx - tlx) * (bry - tly) * en;
    float iou = ai / (gw * gh + pw * ph - ai + 1e-16f);
    return (iou > 0.3f && pw > 2.f && ph > 2.f);
}

// ---- fused: crop + mu/sigma (blocks 0..959) | validity compaction (block 960) ----
__global__ __launch_bounds__(256) void k_crop_valid(const float* __restrict__ imgs,
                                                    const float* __restrict__ gt,
                                                    const float* __restrict__ pr,
                                                    float* __restrict__ crops,
                                                    float* __restrict__ mus,
                                                    float* __restrict__ sigs,
                                                    int* __restrict__ list,
                                                    int* __restrict__ count) {
    const int blk = blockIdx.x;
    const int t = threadIdx.x;
    const int wave = t >> 6, lane = t & 63;

    if (blk == 3 * NCROP) {
        // ---- validity -> compact list: 2-pass wave-local ballot, 1 barrier ----
        __shared__ int s_wcnt[4];
        int cnt = 0;
#pragma unroll 1
        for (int i = 0; i < 16; ++i) {
            unsigned long long m = __ballot(pair_valid(gt, pr, wave * 1024 + i * 64 + lane));
            cnt += __popcll(m);
        }
        if (lane == 0) s_wcnt[wave] = cnt;
        __syncthreads();
        int base = 0;
#pragma unroll
        for (int w = 0; w < 4; ++w)
            if (w < wave) base += s_wcnt[w];
#pragma unroll 1
        for (int i = 0; i < 16; ++i) {
            int idx = wave * 1024 + i * 64 + lane;
            bool v = pair_valid(gt, pr, idx);
            unsigned long long m = __ballot(v);
            if (v) list[base + __popcll(m & ((1ull << lane) - 1ull))] = idx;
            base += __popcll(m);
        }
        if (t == 0) *count = s_wcnt[0] + s_wcnt[1] + s_wcnt[2] + s_wcnt[3];
        return;
    }

    // ---- crop path: per-thread bilinear indices, float2 gathers ----
    const int crop = blk / 3;
    const int c = blk - crop * 3;
    int b;
    const float* box;
    if (crop < BB * NG) {
        b = crop >> 4;
        box = gt + crop * 4;
    } else {
        int id = crop - BB * NG;
        b = id >> 6;
        box = pr + id * 4;
    }

    __shared__ float cr[SZ][PST];
    __shared__ float t1[SZ][PST];
    __shared__ float t2[SZ][PST];

    // box is wave-uniform -> scalar loads
    float cx = box[0], cy = box[1], bw = box[2], bh = box[3];
    float x0 = fminf(fmaxf(floorf(cx - bw * 0.5f), 0.f), (float)(IW - 1));
    float x1 = fminf(fmaxf(floorf(cx + bw * 0.5f), 0.f), (float)IW);
    float y0 = fminf(fmaxf(floorf(cy - bh * 0.5f), 0.f), (float)(IH - 1));
    float y1 = fminf(fmaxf(floorf(cy + bh * 0.5f), 0.f), (float)IH);
    float wp = fmaxf(x1 - x0, 1.f);
    float hp = fmaxf(y1 - y0, 1.f);
    int xmax = (int)(x0 + wp - 1.f);
    int ymax = (int)(y0 + hp - 1.f);

    const int y = t >> 3;          // thread owns pixels (y, xb..xb+3); row = 8 lanes of ONE wave
    const int xb = (t & 7) * 4;

    float sy = y0 + fminf(fmaxf(((float)y + 0.5f) * hp * (1.f / 32.f) - 0.5f, 0.f), hp - 1.f);
    float fly = floorf(sy);
    int iy0 = (int)fly;
    float fy = sy - fly;
    int iy1 = min(iy0 + 1, ymax);

    const float* ic = imgs + ((size_t)b * 3 + c) * IH * IW;
    const float* r0 = ic + iy0 * IW;
    const float* r1 = ic + iy1 * IW;
    float vv[4];
#pragma unroll
    for (int j = 0; j < 4; ++j) {
        int x = xb + j;
        float sx = x0 + fminf(fmaxf(((float)x + 0.5f) * wp * (1.f / 32.f) - 0.5f, 0.f), wp - 1.f);
        float flx = floorf(sx);
        int ix0 = (int)flx;
        float fx = sx - flx;
        // float2 gather (r10): clamp edge has weight exactly 0 -> bitwise identical
        int ixb = max(min(ix0, xmax - 1), 0);
        bool cl = (ix0 > ixb);
        float2 q0 = *(const float2*)(r0 + ixb);
        float2 q1 = *(const float2*)(r1 + ixb);
        float v00 = cl ? q0.y : q0.x;
        float v01 = q0.y;
        float v10 = cl ? q1.y : q1.x;
        float v11 = q1.y;
        vv[j] = v00 * (1.f - fy) * (1.f - fx) + v01 * (1.f - fy) * fx +
                v10 * fy * (1.f - fx) + v11 * fy * fx;
        cr[y][x] = vv[j];
    }
    float* dst = crops + (size_t)crop * NPIX + c * CPIX + t * 4;
    *(float4*)dst = make_float4(vv[0], vv[1], vv[2], vv[3]);
    // NO barrier: h-conv of row y reads cr[y][*], written by this wave only (r12)

    constexpr float GW[WIN] = GW_INIT;
    // horizontal pass on x and x^2 (wave-synchronous)
#pragma unroll
    for (int j = 0; j < 4; ++j) {
        int x = xb + j;
        float a1 = 0.f, a2 = 0.f;
#pragma unroll
        for (int k = 0; k < WIN; ++k) {
            int xx = x + k - HALF;
            if (xx >= 0 && xx < SZ) {
                float v = cr[y][xx];
                a1 += GW[k] * v;
                a2 += GW[k] * v * v;
            }
        }
        t1[y][x] = a1;
        t2[y][x] = a2;
    }
    __syncthreads();   // v-conv reads t1/t2 rows +-5: cross-wave
    // vertical pass
    float m[4], s[4];
#pragma unroll
    for (int j = 0; j < 4; ++j) {
        int x = xb + j;
        float a1 = 0.f, a2 = 0.f;
#pragma unroll
        for (int k = 0; k < WIN; ++k) {
            int yy = y + k - HALF;
            if (yy >= 0 && yy < SZ) {
                a1 += GW[k] * t1[yy][x];
                a2 += GW[k] * t2[yy][x];
            }
        }
        m[j] = a1;
        s[j] = a2 - a1 * a1;
    }
    float* mdst = mus + (size_t)crop * NPIX + c * CPIX + t * 4;
    float* sdst = sigs + (size_t)crop * NPIX + c * CPIX + t * 4;
    *(float4*)mdst = make_float4(m[0], m[1], m[2], m[3]);
    *(float4*)sdst = make_float4(s[0], s[1], s[2], s[3]);
}

// ---- per-(valid-pair, channel) SSIM + L1; unique-cell stores (r3/r7-measured-fast) ----
__global__ __launch_bounds__(256) void k_pair(const int* __restrict__ list,
                                              const int* __restrict__ count,
                                              const float* __restrict__ crops,
                                              const float* __restrict__ mus,
                                              const float* __restrict__ sigs,
                                              float* __restrict__ pairL1,
                                              float* __restrict__ pairSS) {
    const int c = blockIdx.x;      // 0..2
    const int n = *count;
    const int t = threadIdx.x;
    const int y = t >> 3;          // row = 8 lanes of ONE wave
    const int xb = (t & 7) * 4;
    const int wave = t >> 6, lane = t & 63;

    __shared__ float gp[SZ][PST];
    __shared__ float tmp[SZ][PST];
    __shared__ float rl[4], rs[4];
    constexpr float GW[WIN] = GW_INIT;

    for (int slot = blockIdx.y; slot < n; slot += NSLOT) {
        const int pair = list[slot];
        const int b = pair >> 10;
        const int r = pair & 1023;
        const int gi = r >> 6, pi = r & 63;
        const size_t goff = (size_t)(b * NG + gi) * NPIX + c * CPIX;
        const size_t poff = (size_t)(BB * NG + b * NP + pi) * NPIX + c * CPIX;

        float4 gv = *(const float4*)(crops + goff + t * 4);
        float4 pv = *(const float4*)(crops + poff + t * 4);
        // hoist mu/sigma loads: in flight across both conv phases
        float4 mg = *(const float4*)(mus + goff + t * 4);
        float4 mp = *(const float4*)(mus + poff + t * 4);
        float4 sg = *(const float4*)(sigs + goff + t * 4);
        float4 sp = *(const float4*)(sigs + poff + t * 4);

        float l1 = fabsf(gv.x - pv.x) + fabsf(gv.y - pv.y) +
                   fabsf(gv.z - pv.z) + fabsf(gv.w - pv.w);
        gp[y][xb + 0] = gv.x * pv.x;
        gp[y][xb + 1] = gv.y * pv.y;
        gp[y][xb + 2] = gv.z * pv.z;
        gp[y][xb + 3] = gv.w * pv.w;
        // NO barrier: h-conv of row y reads gp[y][*], written by this wave only (r12).
        // gp row ownership is iteration-invariant, so no cross-iter hazard either.

#pragma unroll
        for (int j = 0; j < 4; ++j) {
            int x = xb + j;
            float a = 0.f;
#pragma unroll
            for (int k = 0; k < WIN; ++k) {
                int xx = x + k - HALF;
                if (xx >= 0 && xx < SZ) a += GW[k] * gp[y][xx];
            }
            tmp[y][x] = a;
        }
        __syncthreads();   // A: v-conv reads tmp rows +-5 (cross-wave)

        float mgv[4] = {mg.x, mg.y, mg.z, mg.w};
        float mpv[4] = {mp.x, mp.y, mp.z, mp.w};
        float sgv[4] = {sg.x, sg.y, sg.z, sg.w};
        float spv[4] = {sp.x, sp.y, sp.z, sp.w};
        float ss = 0.f;
#pragma unroll
        for (int j = 0; j < 4; ++j) {
            int x = xb + j;
            float a = 0.f;
#pragma unroll
            for (int k = 0; k < WIN; ++k) {
                int yy = y + k - HALF;
                if (yy >= 0 && yy < SZ) a += GW[k] * tmp[yy][x];
            }
            float m1 = mgv[j], m2 = mpv[j];
            float sgp = a - m1 * m2;
            float num = (2.f * m1 * m2 + SSIM_C1) * (2.f * sgp + SSIM_C2);
            float den = (m1 * m1 + m2 * m2 + SSIM_C1) * (sgv[j] + spv[j] + SSIM_C2);
            ss += num / den;
        }

        // block reduction: 64-lane shuffle, then LDS across 4 waves
#pragma unroll
        for (int off = 32; off > 0; off >>= 1) {
            l1 += __shfl_down(l1, off);
            ss += __shfl_down(ss, off);
        }
        if (lane == 0) { rl[wave] = l1; rs[wave] = ss; }
        __syncthreads();   // B: covers rl/rs read below AND next iter's tmp rewrite
        if (t == 0) {
            pairL1[slot * 3 + c] = rl[0] + rl[1] + rl[2] + rl[3];
            pairSS[slot * 3 + c] = rs[0] + rs[1] + rs[2] + rs[3];
        }
    }
}

// ---- finalize: deterministic reduction over compact results ----
__global__ __launch_bounds__(256) void k_final(const int* __restrict__ count,
                                               const float* __restrict__ pairL1,
                                               const float* __restrict__ pairSS,
                                               float* __restrict__ out) {
    const int n3 = (*count) * 3;
    const int t = threadIdx.x;
    float L = 0.f, S = 0.f;
    for (int i = t; i < n3; i += 256) {
        L += pairL1[i];
        S += pairSS[i];
    }
    __shared__ float rl[4], rs[4];
#pragma unroll
    for (int off = 32; off > 0; off >>= 1) {
        L += __shfl_down(L, off);
        S += __shfl_down(S, off);
    }
    const int wave = t >> 6, lane = t & 63;
    if (lane == 0) { rl[wave] = L; rs[wave] = S; }
    __syncthreads();
    if (t == 0) {
        float cnt = (float)(*count);
        float Lt = (rl[0] + rl[1] + rl[2] + rl[3]) * (1.0f / (255.0f * (float)NPIX));
        float St = (rs[0] + rs[1] + rs[2] + rs[3]) * (1.0f / (float)NPIX);
        float m = fmaxf(cnt, 1.f);
        float loss = Lt / m + 1.f - St / m;
        out[0] = (cnt > 0.f) ? loss : 0.f;
    }
}

extern "C" void kernel_launch(void* const* d_in, const int* in_sizes, int n_in,
                              void* d_out, int out_size, void* d_ws, size_t ws_size,
                              hipStream_t stream) {
    const float* imgs = (const float*)d_in[0];  // (4,3,640,640)
    const float* gt = (const float*)d_in[1];    // (4,16,4)
    const float* pr = (const float*)d_in[2];    // (4,64,4)

    float* ws = (float*)d_ws;
    float* crops = ws;                                   // 320*3072
    float* mus = crops + (size_t)NCROP * NPIX;
    float* sigs = mus + (size_t)NCROP * NPIX;
    float* pairL1 = sigs + (size_t)NCROP * NPIX;         // 4096*3
    float* pairSS = pairL1 + (size_t)NPAIR * 3;          // 4096*3
    int* list = (int*)(pairSS + (size_t)NPAIR * 3);      // 4096
    int* count = list + NPAIR;                           // 1

    k_crop_valid<<<3 * NCROP + 1, 256, 0, stream>>>(imgs, gt, pr, crops, mus, sigs,
                                                    list, count);
    k_pair<<<dim3(3, NSLOT), 256, 0, stream>>>(list, count, crops, mus, sigs,
                                               pairL1, pairSS);
    k_final<<<1, 256, 0, stream>>>(count, pairL1, pairSS, (float*)d_out);
}

// Round 13
// 88.045 us; speedup vs baseline: 1.0308x; 1.0078x over previous
//
#include <hip/hip_runtime.h>
#include <math.h>

#define WIN 11
#define HALF 5
#define SZ 32
#define PST 33          /* padded LDS row stride */
#define BB 4
#define NG 16
#define NP 64
#define IH 640
#define IW 640
#define CPIX 1024       /* 32*32 per channel */
#define NPIX 3072       /* 3*32*32 per crop */
#define NCROP 320       /* 64 gt + 256 pred */
#define NPAIR 4096      /* 4*16*64 */
#define NSLOT 512       /* k_pair y-blocks per channel */
#define SSIM_C1 6.5025f
#define SSIM_C2 58.5225f

// exp(-(i-5)^2/4.5)/sum — 11-tap Gaussian, sigma=1.5, compile-time
#define GW_INIT {0.001028379f, 0.007598757f, 0.036000791f, 0.109360748f, \
                 0.213005174f, 0.266011868f, 0.213005174f, 0.109360748f, \
                 0.036000791f, 0.007598757f, 0.001028379f}

// FINAL CONFIG (r10, measured best 87.45 µs). Session lessons:
//  - NO __threadfence (r5: device-scope fence flushes per-XCD L2; +100 µs over 1.5k blocks).
//  - NO contended fp atomicAdd accumulation (r2/r6 vs r3/r7: +16 µs); unique-cell
//    stores + tiny reduce kernel.
//  - NO memset dispatch: ballot compaction writes count/list with plain stores.
//  - r8: do NOT re-gather crops per pair (scattered gathers are the expensive op).
//  - r9: do NOT move per-crop stats into the per-pair kernel (2.8x conv work).
//  - r10: float2 bilinear gather (16->8 loads) = ~1 µs win.
//  - r11: halo-split x2 regressed (1.31x gathers beat occupancy gain).
//  - r12: wave-local barrier removal neutral (waves stall on memory either way).
//  Remaining time is harness fill (~45 µs) + dispatch ramps + first-touch
//  gather latency — probed from six directions at <=±1 µs each.

__device__ __forceinline__ bool pair_valid(const float* __restrict__ gt,
                                           const float* __restrict__ pr, int idx) {
    int b = idx >> 10;
    int r = idx & 1023;
    int gi = r >> 6, pi = r & 63;
    const float* g = gt + (b * NG + gi) * 4;
    const float* p = pr + (b * NP + pi) * 4;
    float gx = g[0], gy = g[1], gw = g[2], gh = g[3];
    float px = p[0], py = p[1], pw = p[2], ph = p[3];
    float tlx = fmaxf(gx - gw * 0.5f, px - pw * 0.5f);
    float tly = fmaxf(gy - gh * 0.5f, py - ph * 0.5f);
    float brx = fminf(gx + gw * 0.5f, px + pw * 0.5f);
    float bry = fminf(gy + gh * 0.5f, py + ph * 0.5f);
    float en = ((tlx < brx) && (tly < bry)) ? 1.f : 0.f;
    float ai = (brx - tlx) * (bry - tly) * en;
    float iou = ai / (gw * gh + pw * ph - ai + 1e-16f);
    return (iou > 0.3f && pw > 2.f && ph > 2.f);
}

// ---- fused: crop + mu/sigma (blocks 0..959) | validity compaction (block 960) ----
__global__ __launch_bounds__(256) void k_crop_valid(const float* __restrict__ imgs,
                                                    const float* __restrict__ gt,
                                                    const float* __restrict__ pr,
                                                    float* __restrict__ crops,
                                                    float* __restrict__ mus,
                                                    float* __restrict__ sigs,
                                                    int* __restrict__ list,
                                                    int* __restrict__ count) {
    const int blk = blockIdx.x;
    const int t = threadIdx.x;
    const int wave = t >> 6, lane = t & 63;

    if (blk == 3 * NCROP) {
        // ---- validity -> compact list: 2-pass wave-local ballot, 1 barrier ----
        __shared__ int s_wcnt[4];
        int cnt = 0;
#pragma unroll 1
        for (int i = 0; i < 16; ++i) {
            unsigned long long m = __ballot(pair_valid(gt, pr, wave * 1024 + i * 64 + lane));
            cnt += __popcll(m);
        }
        if (lane == 0) s_wcnt[wave] = cnt;
        __syncthreads();
        int base = 0;
#pragma unroll
        for (int w = 0; w < 4; ++w)
            if (w < wave) base += s_wcnt[w];
#pragma unroll 1
        for (int i = 0; i < 16; ++i) {
            int idx = wave * 1024 + i * 64 + lane;
            bool v = pair_valid(gt, pr, idx);
            unsigned long long m = __ballot(v);
            if (v) list[base + __popcll(m & ((1ull << lane) - 1ull))] = idx;
            base += __popcll(m);
        }
        if (t == 0) *count = s_wcnt[0] + s_wcnt[1] + s_wcnt[2] + s_wcnt[3];
        return;
    }

    // ---- crop path: per-thread bilinear indices, float2 gathers ----
    const int crop = blk / 3;
    const int c = blk - crop * 3;
    int b;
    const float* box;
    if (crop < BB * NG) {
        b = crop >> 4;
        box = gt + crop * 4;
    } else {
        int id = crop - BB * NG;
        b = id >> 6;
        box = pr + id * 4;
    }

    __shared__ float cr[SZ][PST];
    __shared__ float t1[SZ][PST];
    __shared__ float t2[SZ][PST];

    // box is wave-uniform -> scalar loads
    float cx = box[0], cy = box[1], bw = box[2], bh = box[3];
    float x0 = fminf(fmaxf(floorf(cx - bw * 0.5f), 0.f), (float)(IW - 1));
    float x1 = fminf(fmaxf(floorf(cx + bw * 0.5f), 0.f), (float)IW);
    float y0 = fminf(fmaxf(floorf(cy - bh * 0.5f), 0.f), (float)(IH - 1));
    float y1 = fminf(fmaxf(floorf(cy + bh * 0.5f), 0.f), (float)IH);
    float wp = fmaxf(x1 - x0, 1.f);
    float hp = fmaxf(y1 - y0, 1.f);
    int xmax = (int)(x0 + wp - 1.f);
    int ymax = (int)(y0 + hp - 1.f);

    const int y = t >> 3;          // thread owns pixels (y, xb..xb+3)
    const int xb = (t & 7) * 4;

    float sy = y0 + fminf(fmaxf(((float)y + 0.5f) * hp * (1.f / 32.f) - 0.5f, 0.f), hp - 1.f);
    float fly = floorf(sy);
    int iy0 = (int)fly;
    float fy = sy - fly;
    int iy1 = min(iy0 + 1, ymax);

    const float* ic = imgs + ((size_t)b * 3 + c) * IH * IW;
    const float* r0 = ic + iy0 * IW;
    const float* r1 = ic + iy1 * IW;
    float vv[4];
#pragma unroll
    for (int j = 0; j < 4; ++j) {
        int x = xb + j;
        float sx = x0 + fminf(fmaxf(((float)x + 0.5f) * wp * (1.f / 32.f) - 0.5f, 0.f), wp - 1.f);
        float flx = floorf(sx);
        int ix0 = (int)flx;
        float fx = sx - flx;
        // float2 gather: ix1==ix0+1 except at the clamp edge; clamped/degenerate
        // lanes have fx==0 or select f.y, so result is bitwise identical to the
        // 4-scalar-load version (0-weight taps multiply a finite value).
        int ixb = max(min(ix0, xmax - 1), 0);
        bool cl = (ix0 > ixb);     // ix0 was at xmax: duplicate high element
        float2 q0 = *(const float2*)(r0 + ixb);
        float2 q1 = *(const float2*)(r1 + ixb);
        float v00 = cl ? q0.y : q0.x;
        float v01 = q0.y;
        float v10 = cl ? q1.y : q1.x;
        float v11 = q1.y;
        vv[j] = v00 * (1.f - fy) * (1.f - fx) + v01 * (1.f - fy) * fx +
                v10 * fy * (1.f - fx) + v11 * fy * fx;
        cr[y][x] = vv[j];
    }
    float* dst = crops + (size_t)crop * NPIX + c * CPIX + t * 4;
    *(float4*)dst = make_float4(vv[0], vv[1], vv[2], vv[3]);
    __syncthreads();

    constexpr float GW[WIN] = GW_INIT;
    // horizontal pass on x and x^2
#pragma unroll
    for (int j = 0; j < 4; ++j) {
        int x = xb + j;
        float a1 = 0.f, a2 = 0.f;
#pragma unroll
        for (int k = 0; k < WIN; ++k) {
            int xx = x + k - HALF;
            if (xx >= 0 && xx < SZ) {
                float v = cr[y][xx];
                a1 += GW[k] * v;
                a2 += GW[k] * v * v;
            }
        }
        t1[y][x] = a1;
        t2[y][x] = a2;
    }
    __syncthreads();
    // vertical pass
    float m[4], s[4];
#pragma unroll
    for (int j = 0; j < 4; ++j) {
        int x = xb + j;
        float a1 = 0.f, a2 = 0.f;
#pragma unroll
        for (int k = 0; k < WIN; ++k) {
            int yy = y + k - HALF;
            if (yy >= 0 && yy < SZ) {
                a1 += GW[k] * t1[yy][x];
                a2 += GW[k] * t2[yy][x];
            }
        }
        m[j] = a1;
        s[j] = a2 - a1 * a1;
    }
    float* mdst = mus + (size_t)crop * NPIX + c * CPIX + t * 4;
    float* sdst = sigs + (size_t)crop * NPIX + c * CPIX + t * 4;
    *(float4*)mdst = make_float4(m[0], m[1], m[2], m[3]);
    *(float4*)sdst = make_float4(s[0], s[1], s[2], s[3]);
}

// ---- per-(valid-pair, channel) SSIM + L1; unique-cell stores (r3/r7-measured-fast) ----
__global__ __launch_bounds__(256) void k_pair(const int* __restrict__ list,
                                              const int* __restrict__ count,
                                              const float* __restrict__ crops,
                                              const float* __restrict__ mus,
                                              const float* __restrict__ sigs,
                                              float* __restrict__ pairL1,
                                              float* __restrict__ pairSS) {
    const int c = blockIdx.x;      // 0..2
    const int n = *count;
    const int t = threadIdx.x;
    const int y = t >> 3;
    const int xb = (t & 7) * 4;
    const int wave = t >> 6, lane = t & 63;

    __shared__ float gp[SZ][PST];
    __shared__ float tmp[SZ][PST];
    __shared__ float rl[4], rs[4];
    constexpr float GW[WIN] = GW_INIT;

    for (int slot = blockIdx.y; slot < n; slot += NSLOT) {
        const int pair = list[slot];
        const int b = pair >> 10;
        const int r = pair & 1023;
        const int gi = r >> 6, pi = r & 63;
        const size_t goff = (size_t)(b * NG + gi) * NPIX + c * CPIX;
        const size_t poff = (size_t)(BB * NG + b * NP + pi) * NPIX + c * CPIX;

        float4 gv = *(const float4*)(crops + goff + t * 4);
        float4 pv = *(const float4*)(crops + poff + t * 4);
        // hoist mu/sigma loads: in flight across both conv phases
        float4 mg = *(const float4*)(mus + goff + t * 4);
        float4 mp = *(const float4*)(mus + poff + t * 4);
        float4 sg = *(const float4*)(sigs + goff + t * 4);
        float4 sp = *(const float4*)(sigs + poff + t * 4);

        float l1 = fabsf(gv.x - pv.x) + fabsf(gv.y - pv.y) +
                   fabsf(gv.z - pv.z) + fabsf(gv.w - pv.w);
        gp[y][xb + 0] = gv.x * pv.x;
        gp[y][xb + 1] = gv.y * pv.y;
        gp[y][xb + 2] = gv.z * pv.z;
        gp[y][xb + 3] = gv.w * pv.w;
        __syncthreads();

#pragma unroll
        for (int j = 0; j < 4; ++j) {
            int x = xb + j;
            float a = 0.f;
#pragma unroll
            for (int k = 0; k < WIN; ++k) {
                int xx = x + k - HALF;
                if (xx >= 0 && xx < SZ) a += GW[k] * gp[y][xx];
            }
            tmp[y][x] = a;
        }
        __syncthreads();

        float mgv[4] = {mg.x, mg.y, mg.z, mg.w};
        float mpv[4] = {mp.x, mp.y, mp.z, mp.w};
        float sgv[4] = {sg.x, sg.y, sg.z, sg.w};
        float spv[4] = {sp.x, sp.y, sp.z, sp.w};
        float ss = 0.f;
#pragma unroll
        for (int j = 0; j < 4; ++j) {
            int x = xb + j;
            float a = 0.f;
#pragma unroll
            for (int k = 0; k < WIN; ++k) {
                int yy = y + k - HALF;
                if (yy >= 0 && yy < SZ) a += GW[k] * tmp[yy][x];
            }
            float m1 = mgv[j], m2 = mpv[j];
            float sgp = a - m1 * m2;
            float num = (2.f * m1 * m2 + SSIM_C1) * (2.f * sgp + SSIM_C2);
            float den = (m1 * m1 + m2 * m2 + SSIM_C1) * (sgv[j] + spv[j] + SSIM_C2);
            ss += num / den;
        }

        // block reduction: 64-lane shuffle, then LDS across 4 waves
#pragma unroll
        for (int off = 32; off > 0; off >>= 1) {
            l1 += __shfl_down(l1, off);
            ss += __shfl_down(ss, off);
        }
        if (lane == 0) { rl[wave] = l1; rs[wave] = ss; }
        __syncthreads();
        if (t == 0) {
            pairL1[slot * 3 + c] = rl[0] + rl[1] + rl[2] + rl[3];
            pairSS[slot * 3 + c] = rs[0] + rs[1] + rs[2] + rs[3];
        }
    }
}

// ---- finalize: deterministic reduction over compact results ----
__global__ __launch_bounds__(256) void k_final(const int* __restrict__ count,
                                               const float* __restrict__ pairL1,
                                               const float* __restrict__ pairSS,
                                               float* __restrict__ out) {
    const int n3 = (*count) * 3;
    const int t = threadIdx.x;
    float L = 0.f, S = 0.f;
    for (int i = t; i < n3; i += 256) {
        L += pairL1[i];
        S += pairSS[i];
    }
    __shared__ float rl[4], rs[4];
#pragma unroll
    for (int off = 32; off > 0; off >>= 1) {
        L += __shfl_down(L, off);
        S += __shfl_down(S, off);
    }
    const int wave = t >> 6, lane = t & 63;
    if (lane == 0) { rl[wave] = L; rs[wave] = S; }
    __syncthreads();
    if (t == 0) {
        float cnt = (float)(*count);
        float Lt = (rl[0] + rl[1] + rl[2] + rl[3]) * (1.0f / (255.0f * (float)NPIX));
        float St = (rs[0] + rs[1] + rs[2] + rs[3]) * (1.0f / (float)NPIX);
        float m = fmaxf(cnt, 1.f);
        float loss = Lt / m + 1.f - St / m;
        out[0] = (cnt > 0.f) ? loss : 0.f;
    }
}

extern "C" void kernel_launch(void* const* d_in, const int* in_sizes, int n_in,
                              void* d_out, int out_size, void* d_ws, size_t ws_size,
                              hipStream_t stream) {
    const float* imgs = (const float*)d_in[0];  // (4,3,640,640)
    const float* gt = (const float*)d_in[1];    // (4,16,4)
    const float* pr = (const float*)d_in[2];    // (4,64,4)

    float* ws = (float*)d_ws;
    float* crops = ws;                                   // 320*3072
    float* mus = crops + (size_t)NCROP * NPIX;
    float* sigs = mus + (size_t)NCROP * NPIX;
    float* pairL1 = sigs + (size_t)NCROP * NPIX;         // 4096*3
    float* pairSS = pairL1 + (size_t)NPAIR * 3;          // 4096*3
    int* list = (int*)(pairSS + (size_t)NPAIR * 3);      // 4096
    int* count = list + NPAIR;                           // 1

    k_crop_valid<<<3 * NCROP + 1, 256, 0, stream>>>(imgs, gt, pr, crops, mus, sigs,
                                                    list, count);
    k_pair<<<dim3(3, NSLOT), 256, 0, stream>>>(list, count, crops, mus, sigs,
                                               pairL1, pairSS);
    k_final<<<1, 256, 0, stream>>>(count, pairL1, pairSS, (float*)d_out);
}